// Round 8
// baseline (926.283 us; speedup 1.0000x reference)
//
#include <hip/hip_runtime.h>

// LSTM feedback net: B=16384, T=48 warmup, F=4, UNITS=256, 24 AR steps.
// R19 = R18 (pred-folded, 742us) + wave-pair weight-stream sharing:
//  - Model: GEMM phase is L2-fabric-bound (557KB unique weight bytes/CU/step
//    ~ 44 B/cyc vs ~56 B/cyc L2 ceiling). MFMA pipe ~10% busy per SIMD.
//  - Re-split: N-split 4 x M-split 2. pair p=w&3 (= SIMD id), m-tile mt=w>>2.
//    Waves (w, w+4) are co-resident on the SAME SIMD and read the IDENTICAL
//    64-col weight stream (8KB/tile); unique bytes/CU/step halve to ~280KB.
//    Partner loads hit L1/MSHR-merge; pair is self-stabilizing (laggard hits
//    the leader's fills). acc stays 128 AGPR (split-invariant: 8 col-tiles
//    x 1 m-tile). LDS h-reads per stage halve (1 frag).
//  - aw ring 3->2 (8 frags/tile x 2 = 64 VGPR). Ring-2 cover = 2 stages
//    (~2.6K cyc) >> load latency; R13 proved ring depth >3 is neutral.
//    Epilogue stages 15,16 load NEXT-step tiles {1,0} into slots {1,0}
//    (parity-correct across the 17-tile step, R14 lesson).
//  - Weight layout regrouped: frag idx = kt*32 + p*8 + (g*2+su), cols
//    n = 256g + 64p + 32su + lane31. Same K-order, same math per element
//    -> bit-identical to R18: absmax must repeat 0.00390625.
// Budget: acc 128 AGPR + VGPR (aw64 + hb8 + c32 + misc~20) <= 256, no spill.

typedef unsigned short u16;
typedef __attribute__((ext_vector_type(8))) short bf16x8;
typedef __attribute__((ext_vector_type(4))) float f32x4;
typedef __attribute__((ext_vector_type(16))) float f32x16;

#define PITCH 296    // hext row pitch, elems (592 B/row)
#define HB 18944     // elems per h buffer (64*296)
#define WARM 48
#define STEPS 71     // 48 warmup + 23 AR cell steps
#define LOG2E  1.442695041f
#define LOG2E2 2.885390082f

__device__ __forceinline__ u16 f2bf(float f) {
    unsigned u = __float_as_uint(f);
    u += 0x7FFFu + ((u >> 16) & 1u);   // round-to-nearest-even
    return (u16)(u >> 16);
}

// pack 2 f32 -> 2 bf16 (RNE), one VOP3 instr
__device__ __forceinline__ unsigned pk_bf16(float a, float b) {
    unsigned d;
    asm("v_cvt_pk_bf16_f32 %0, %1, %2" : "=v"(d) : "v"(a), "v"(b));
    return d;
}

// LDS-only barrier: drain LDS ops, NOT vmcnt -> global loads stay in flight.
__device__ __forceinline__ void sync_lds() {
    asm volatile("s_waitcnt lgkmcnt(0)\n\ts_barrier" ::: "memory");
}

// consumer: spin until all 4 flags >= tgt, then fence (R17-proven pattern)
__device__ __forceinline__ void wait4(const int* f, int tgt) {
    for (;;) {
        int a = ((volatile const int*)f)[0];
        int b = ((volatile const int*)f)[1];
        int c = ((volatile const int*)f)[2];
        int d = ((volatile const int*)f)[3];
        if (a >= tgt && b >= tgt && c >= tgt && d >= tgt) break;
    }
    asm volatile("" ::: "memory");
}

// ---- prep: 32x32x16 A-fragments of W' (K=272 x N=1024), 17 kt tiles.
// R19 frag order: idx = kt*32 + p*8 + a, a = g*2+su (pair-major, so a wave
// pair's 8 frags are one contiguous 8KB block -> shared stream).
// Lane l of frag (kt,p,a): W'[kt*16+(l>>5)*8+j][256g+64p+32su+(l&31)].
// K rows: 0..255 Wh, 256..259 Wx, 260 bias. Cols scaled log2e / 2log2e (g).
// wd16: 9 K32-chunks of Wd^T in 16x16x32 A-layout (m=feature), unscaled.
__global__ void prep_weights(const float* __restrict__ Wx,
                             const float* __restrict__ Wh,
                             const float* __restrict__ b,
                             const float* __restrict__ Wd,
                             const float* __restrict__ bd,
                             u16* __restrict__ whext,
                             u16* __restrict__ wdp) {
    int idx = blockIdx.x * 256 + threadIdx.x;   // one thread per 16B chunk
    if (idx < 34816) {                          // 17 kt * 4 p * 8 a * 64 lanes
        int lane = idx & 63;
        int fr = idx >> 6;
        int a = fr & 7;
        int p2 = (fr >> 3) & 3;
        int kt = fr >> 5;
        int g = a >> 1;
        int su = a & 1;
        int k0 = kt * 16 + (lane >> 5) * 8;
        int n = 256 * g + 64 * p2 + 32 * su + (lane & 31);
        float sc = (g == 2) ? LOG2E2 : LOG2E;
        u16 v[8];
#pragma unroll
        for (int j = 0; j < 8; ++j) {
            int k = k0 + j;
            float f = 0.0f;
            if (k < 256) f = Wh[k * 1024 + n];
            else if (k < 260) f = Wx[(k - 256) * 1024 + n];
            else if (k == 260) f = b[n];
            v[j] = f2bf(f * sc);
        }
        ushort4* dst = (ushort4*)(whext + (size_t)idx * 8);
        dst[0] = make_ushort4(v[0], v[1], v[2], v[3]);
        dst[1] = make_ushort4(v[4], v[5], v[6], v[7]);
    } else if (idx < 34816 + 576) {             // wd16: 9 chunks x 64 lanes
        int id2 = idx - 34816;
        int lane = id2 & 63;
        int kc = id2 >> 6;
        int m = lane & 15;                      // feature row
        int k0 = kc * 32 + (lane >> 4) * 8;
        u16 v[8];
#pragma unroll
        for (int j = 0; j < 8; ++j) {
            int k = k0 + j;
            float f = 0.0f;
            if (m < 4) {
                if (k < 256) f = Wd[k * 4 + m];
                else if (k == 260) f = bd[m];
            }
            v[j] = f2bf(f);
        }
        ushort4* dst = (ushort4*)(wdp + (size_t)id2 * 8);
        dst[0] = make_ushort4(v[0], v[1], v[2], v[3]);
        dst[1] = make_ushort4(v[4], v[5], v[6], v[7]);
    }
}

// pair base wpw = whext + p*8192B; per kt stride 32768B; 8 frags at 1KB steps
// (imm offsets <= 3072 via split base _q = _p+4096, keeps 13-bit imm range).
#define WL(DST, T) do {                                                       \
    const char* _p = wpw + ((size_t)(T) << 15);                               \
    DST[0] = *(const bf16x8*)(_p + voffl);                                    \
    DST[1] = *(const bf16x8*)(_p + voffl + 1024);                             \
    DST[2] = *(const bf16x8*)(_p + voffl + 2048);                             \
    DST[3] = *(const bf16x8*)(_p + voffl + 3072);                             \
    const char* _q = _p + 4096;                                               \
    DST[4] = *(const bf16x8*)(_q + voffl);                                    \
    DST[5] = *(const bf16x8*)(_q + voffl + 1024);                             \
    DST[6] = *(const bf16x8*)(_q + voffl + 2048);                             \
    DST[7] = *(const bf16x8*)(_q + voffl + 3072);                             \
} while (0)

#define HLD(DST, T) do { DST = *(const bf16x8*)&hr[hrow + (T) * 16]; } while (0)

#define MT(WA, HBX)                                                           \
    _Pragma("unroll") for (int a = 0; a < 8; ++a)                             \
        acc[a] = __builtin_amdgcn_mfma_f32_32x32x16_bf16(                     \
            WA[a], HBX, acc[a], 0, 0, 0);

// one pipeline stage: consume tile K from (AWX,HBX), refill both with K+2
#define STG(K, AWX, HBX) do { MT(AWX, HBX); WL(AWX, (K) + 2); HLD(HBX, (K) + 2); } while (0)

__global__ __launch_bounds__(512, 2) void lstm_main(
    const float* __restrict__ x, const u16* __restrict__ whext,
    const u16* __restrict__ wdp, float* __restrict__ out) {
    __shared__ __align__(16) u16 hbuf[2 * HB];   // h double buffer
    __shared__ int flag16[4];   // pred-feedback publish counters (monotone)

    const int tid = threadIdx.x;
    const int w = tid >> 6;
    const int p = w & 3;           // pair id = SIMD id; cols [64p, 64p+64)
    const int mt = w >> 2;         // m-tile: batch rows [32mt, 32mt+32)
    const int l = tid & 63;
    const int l31 = l & 31;
    const int lh = l >> 5;
    const long long rowBase = (long long)blockIdx.x * 64;

    {   // zero both h buffers (incl. pad cols 261..287 -- stay zero forever)
        int4 z = make_int4(0, 0, 0, 0);
        for (int i = tid; i < 4736; i += 512) ((int4*)hbuf)[i] = z;
        if (tid < 4) flag16[tid] = 0;
    }
    sync_lds();
    if (tid < 64) {
        hbuf[tid * PITCH + 260] = (u16)0x3F80;        // bias-1 col, buffer 0
        hbuf[HB + tid * PITCH + 260] = (u16)0x3F80;   // and buffer 1
        const float4 xv = *(const float4*)(x + (rowBase + tid) * 192);
        uint2* q = (uint2*)&hbuf[tid * PITCH + 256];   // x_0 -> buffer 0
        *q = make_uint2(pk_bf16(xv.x, xv.y), pk_bf16(xv.z, xv.w));
    }

    const char* __restrict__ wpw = (const char*)whext + (size_t)p * 8192;
    const char* __restrict__ dp = (const char*)wdp;
    const int voffl = l * 16;
    const int hrow = (32 * mt + l31) * PITCH + lh * 8;   // B-frag row (elems)

    f32x16 c[2] = {};      // cell state: su -> unit 64p+32su+(r&3)+8*(r>>2)+4lh
                           // batch = 32mt + l31
    bf16x8 aw0[8], aw1[8];   // ring-2 weight frags: tile k in aw(k&1)
    bf16x8 hb0, hb1;         // ring-2 h frags
    WL(aw0, 0);            // tiles 0,1 in flight across the first barrier
    WL(aw1, 1);

    for (int step = 0; step < STEPS; ++step) {
        const u16* hr = hbuf + (step & 1) * HB;      // read buffer
        u16* hrw = hbuf + (step & 1) * HB;           // same buffer, writable
        u16* hw = hbuf + ((step & 1) ^ 1) * HB;      // write buffer

        // wave 0: issue next warmup x load now; used ~10us later at step end
        float4 xv = make_float4(0.f, 0.f, 0.f, 0.f);
        if (w == 0 && step < WARM - 1)
            xv = *(const float4*)(x + (rowBase + l) * 192 + (step + 1) * 4);

        sync_lds();   // hr ready; prior reads of hw done; aw0,aw1 in flight

        // ---- pred for output s = step-WARM, folded into this GEMM phase
        // (R18-proven). Reads hr h-cols 0..255; writes out + feedback x
        // (hr cols 256..259, consumed at stage 14 after wait4(flag16)).
        if (step >= WARM && w < 4) {
            f32x4 pacc = {};
            const int col = l & 15;                     // batch within tile
            const int prow = (16 * w + col) * PITCH + (l >> 4) * 8;
#pragma unroll
            for (int kc = 0; kc < 9; ++kc) {            // K32 chunks 0..8
                bf16x8 hbp = *(const bf16x8*)&hr[prow + kc * 32];
                bf16x8 wap = *(const bf16x8*)(dp + ((size_t)kc * 64 + l) * 16);
                pacc = __builtin_amdgcn_mfma_f32_16x16x32_bf16(wap, hbp, pacc, 0, 0, 0);
            }
            if ((l >> 4) == 0) {   // quad 0: regs 0..3 = features 0..3
                int s = step - WARM;
                int batch = 16 * w + col;
                *(float4*)&out[((rowBase + batch) * 24 + s) * 4] =
                    make_float4(pacc[0], pacc[1], pacc[2], pacc[3]);
                *(uint2*)&hrw[batch * PITCH + 256] =   // feedback as x_step
                    make_uint2(pk_bf16(pacc[0], pacc[1]), pk_bf16(pacc[2], pacc[3]));
            }
            asm volatile("s_waitcnt lgkmcnt(0)" ::: "memory");
            if (l == 0) *(volatile int*)&flag16[w] = step - WARM + 1;
        }

        f32x16 acc[8] = {};      // a = g*2+su
        HLD(hb0, 0);
        HLD(hb1, 1);

        // 17 K-tiles, ring-2. Stage k: MT(aw(k&1), hb(k&1)); refill <- k+2.
#pragma unroll 1
        for (int k = 0; k < 14; k += 2) {   // stages 0..13
            STG(k, aw0, hb0);
            STG(k + 1, aw1, hb1);
        }
        MT(aw0, hb0); WL(aw0, 16);               // stage 14
        if (step >= WARM) wait4(flag16, step - WARM + 1);   // x_step published?
        HLD(hb0, 16);
        MT(aw1, hb1); WL(aw1, 1);                // stage 15; prestage next-1
        MT(aw0, hb0); WL(aw0, 0);                // stage 16; prestage next-0
        // aw0,aw1 now hold NEXT step's tiles 0,1, flying over gates+barrier

        // gates; lane holds batch 32mt+l31, units 64p+32su+(r&3)+8*(r>>2)+4lh.
        // 7 transcendentals/elem: 5 exp2 + 2 rcp. Bit-identical to R18.
#pragma unroll
        for (int su = 0; su < 2; ++su) {
            const int hwrow = (32 * mt + l31) * PITCH + 64 * p + 32 * su + 4 * lh;
#pragma unroll
            for (int q = 0; q < 4; ++q) {
                unsigned pk[2];
#pragma unroll
                for (int hp = 0; hp < 2; ++hp) {
                    float h2[2];
#pragma unroll
                    for (int rr = 0; rr < 2; ++rr) {
                        const int r = q * 4 + hp * 2 + rr;
                        float ei = __builtin_amdgcn_exp2f(-acc[0 + su][r]);
                        float ef = __builtin_amdgcn_exp2f(-acc[2 + su][r]);
                        float eg = __builtin_amdgcn_exp2f(-acc[4 + su][r]);
                        float eo = __builtin_amdgcn_exp2f(-acc[6 + su][r]);
                        float ai = 1.0f + ei, af = 1.0f + ef;
                        float ag = 1.0f + eg, ao = 1.0f + eo;
                        float P  = ai * ag;
                        float rD = __builtin_amdgcn_rcpf(P * af);
                        float cn = fmaf(c[su][r] * P, rD, (1.0f - eg) * af * rD);
                        c[su][r] = cn;
                        float ec = __builtin_amdgcn_exp2f(-LOG2E2 * cn);
                        float rE = __builtin_amdgcn_rcpf(ao * (1.0f + ec));
                        h2[rr] = (1.0f - ec) * rE;
                    }
                    pk[hp] = pk_bf16(h2[0], h2[1]);
                }
                *(uint2*)&hw[hwrow + 8 * q] = make_uint2(pk[0], pk[1]);
            }
        }

        if (step < WARM - 1) {
            if (w == 0) {   // x_{step+1} (prefetched at step top) -> hw
                uint2* q = (uint2*)&hw[l * PITCH + 256];
                *q = make_uint2(pk_bf16(xv.x, xv.y), pk_bf16(xv.z, xv.w));
            }
        }
        // AR steps: pred for this step's h runs at the TOP of the next
        // iteration, overlapped with the GEMM phase (no second barrier).
    }

    // ---- epilogue: last prediction (s = 23) from h_71 (no feedback needed)
    sync_lds();
    if (w < 4) {
        const u16* hf = hbuf + (((STEPS - 1) & 1) ^ 1) * HB;
        f32x4 pacc = {};
        const int col = l & 15;
        const int prow = (16 * w + col) * PITCH + (l >> 4) * 8;
#pragma unroll
        for (int kc = 0; kc < 9; ++kc) {
            bf16x8 hbp = *(const bf16x8*)&hf[prow + kc * 32];
            bf16x8 wap = *(const bf16x8*)(dp + ((size_t)kc * 64 + l) * 16);
            pacc = __builtin_amdgcn_mfma_f32_16x16x32_bf16(wap, hbp, pacc, 0, 0, 0);
        }
        if ((l >> 4) == 0) {
            int batch = 16 * w + col;
            *(float4*)&out[((rowBase + batch) * 24 + 23) * 4] =
                make_float4(pacc[0], pacc[1], pacc[2], pacc[3]);
        }
    }
}

extern "C" void kernel_launch(void* const* d_in, const int* in_sizes, int n_in,
                              void* d_out, int out_size, void* d_ws, size_t ws_size,
                              hipStream_t stream) {
    const float* x  = (const float*)d_in[0];   // [16384,48,4]
    const float* Wx = (const float*)d_in[1];   // [4,1024]
    const float* Wh = (const float*)d_in[2];   // [256,1024]
    const float* b  = (const float*)d_in[3];   // [1024]
    const float* Wd = (const float*)d_in[4];   // [256,4]
    const float* bd = (const float*)d_in[5];   // [4]
    float* out = (float*)d_out;                // [16384,24,4] fp32

    u16* whext = (u16*)d_ws;                        // 17*32*64*16 = 557056 B
    u16* wdp = (u16*)((char*)d_ws + 557056);        // 9216 B

    prep_weights<<<(34816 + 576 + 255) / 256, 256, 0, stream>>>(Wx, Wh, b, Wd, bd, whext, wdp);
    lstm_main<<<256, 512, 0, stream>>>(x, whext, wdp, out);
}

// Round 9
// 723.809 us; speedup vs baseline: 1.2797x; 1.2797x over previous
//
#include <hip/hip_runtime.h>

// LSTM feedback net: B=16384, T=48 warmup, F=4, UNITS=256, 24 AR steps.
// R20 = R18 (pred-folded, 742.8us best) + LDS-PARKED weight tiles 0,1:
//  - R19 post-mortem: per-CU unique weight stream (557KB/step) is invariant
//    (every CU computes all 1024 gate cols for its 64 rows); pacing resource
//    is the CU load-return path. Weights are loop-INVARIANT -> park K-tiles
//    0,1 (64KB = all 8 waves' slices) in LDS once; read via ds_read_b128
//    (separate port). Per-step global weight traffic: 17 -> 15 tiles (-12%).
//  - 15 remaining global tiles (2..16): 15%3==0 so ring-3 slot parity is
//    naturally step-aligned (t=14,15,16 refill next-step tiles 2,3,4 into
//    slots 0,1,2 = exactly where stages t=2,3,4 read them). Desk-checked.
//  - Parked stages use ONE reused awl[4] buffer (VGPR peak stays <=128:
//    awl16 + aw48 + hb16 + c32 + misc ~16; pred temps dead in that window).
//  - LDS: hbuf 75,776 + wlds 65,536 + flags = 141,328 B < 160K.
// Arithmetic bit-identical to R18 -> absmax must repeat 0.00390625.

typedef unsigned short u16;
typedef __attribute__((ext_vector_type(8))) short bf16x8;
typedef __attribute__((ext_vector_type(4))) float f32x4;
typedef __attribute__((ext_vector_type(16))) float f32x16;

#define PITCH 296    // hext row pitch, elems (592 B/row)
#define HB 18944     // elems per h buffer (64*296)
#define WARM 48
#define STEPS 71     // 48 warmup + 23 AR cell steps
#define LOG2E  1.442695041f
#define LOG2E2 2.885390082f

__device__ __forceinline__ u16 f2bf(float f) {
    unsigned u = __float_as_uint(f);
    u += 0x7FFFu + ((u >> 16) & 1u);   // round-to-nearest-even
    return (u16)(u >> 16);
}

// pack 2 f32 -> 2 bf16 (RNE), one VOP3 instr
__device__ __forceinline__ unsigned pk_bf16(float a, float b) {
    unsigned d;
    asm("v_cvt_pk_bf16_f32 %0, %1, %2" : "=v"(d) : "v"(a), "v"(b));
    return d;
}

// LDS-only barrier: drain LDS ops, NOT vmcnt -> global loads stay in flight.
__device__ __forceinline__ void sync_lds() {
    asm volatile("s_waitcnt lgkmcnt(0)\n\ts_barrier" ::: "memory");
}

// consumer: spin until all 4 flags >= tgt, then fence (R17-proven pattern)
__device__ __forceinline__ void wait4(const int* f, int tgt) {
    for (;;) {
        int a = ((volatile const int*)f)[0];
        int b = ((volatile const int*)f)[1];
        int c = ((volatile const int*)f)[2];
        int d = ((volatile const int*)f)[3];
        if (a >= tgt && b >= tgt && c >= tgt && d >= tgt) break;
    }
    asm volatile("" ::: "memory");
}

// ---- prep: 32x32x16 A-fragments of W' (K=272 x N=1024), 17 kt tiles.
// Frag order: idx = kt*32 + wv*4 + g  (g fastest -> imm-offset loads).
// Lane l of a frag holds W'[kt*16+(l>>5)*8+j][256g+32wv+(l&31)], j=0..7.
// K rows: 0..255 Wh, 256..259 Wx, 260 bias. Cols scaled log2e / 2log2e (g).
// wd16: 9 K32-chunks of Wd^T in 16x16x32 A-layout (m=feature), unscaled.
__global__ void prep_weights(const float* __restrict__ Wx,
                             const float* __restrict__ Wh,
                             const float* __restrict__ b,
                             const float* __restrict__ Wd,
                             const float* __restrict__ bd,
                             u16* __restrict__ whext,
                             u16* __restrict__ wdp) {
    int idx = blockIdx.x * 256 + threadIdx.x;   // one thread per 16B chunk
    if (idx < 34816) {                          // 17 kt * 8 wv * 4 g * 64 lanes
        int lane = idx & 63;
        int fr = idx >> 6;
        int g = fr & 3;
        int wv = (fr >> 2) & 7;
        int kt = fr >> 5;
        int k0 = kt * 16 + (lane >> 5) * 8;
        int n = 256 * g + 32 * wv + (lane & 31);
        float sc = (g == 2) ? LOG2E2 : LOG2E;
        u16 v[8];
#pragma unroll
        for (int j = 0; j < 8; ++j) {
            int k = k0 + j;
            float f = 0.0f;
            if (k < 256) f = Wh[k * 1024 + n];
            else if (k < 260) f = Wx[(k - 256) * 1024 + n];
            else if (k == 260) f = b[n];
            v[j] = f2bf(f * sc);
        }
        ushort4* dst = (ushort4*)(whext + (size_t)idx * 8);
        dst[0] = make_ushort4(v[0], v[1], v[2], v[3]);
        dst[1] = make_ushort4(v[4], v[5], v[6], v[7]);
    } else if (idx < 34816 + 576) {             // wd16: 9 chunks x 64 lanes
        int id2 = idx - 34816;
        int lane = id2 & 63;
        int kc = id2 >> 6;
        int m = lane & 15;                      // feature row
        int k0 = kc * 32 + (lane >> 4) * 8;
        u16 v[8];
#pragma unroll
        for (int j = 0; j < 8; ++j) {
            int k = k0 + j;
            float f = 0.0f;
            if (m < 4) {
                if (k < 256) f = Wd[k * 4 + m];
                else if (k == 260) f = bd[m];
            }
            v[j] = f2bf(f);
        }
        ushort4* dst = (ushort4*)(wdp + (size_t)id2 * 8);
        dst[0] = make_ushort4(v[0], v[1], v[2], v[3]);
        dst[1] = make_ushort4(v[4], v[5], v[6], v[7]);
    }
}

// wave base wpw = whext + w*4096B; per kt stride 32768B; per g imm 1024B.
#define WL(DST, T) do {                                                       \
    const char* _p = wpw + ((size_t)(T) << 15);                               \
    DST[0] = *(const bf16x8*)(_p + voffl);                                    \
    DST[1] = *(const bf16x8*)(_p + voffl + 1024);                             \
    DST[2] = *(const bf16x8*)(_p + voffl + 2048);                             \
    DST[3] = *(const bf16x8*)(_p + voffl + 3072);                             \
} while (0)

// parked-tile frag load from LDS (tiles 0,1; wlp = wlds byte base + w*4096)
#define WLL(DST, T) do {                                                      \
    const char* _p = wlp + (T) * 32768;                                       \
    DST[0] = *(const bf16x8*)(_p + voffl);                                    \
    DST[1] = *(const bf16x8*)(_p + voffl + 1024);                             \
    DST[2] = *(const bf16x8*)(_p + voffl + 2048);                             \
    DST[3] = *(const bf16x8*)(_p + voffl + 3072);                             \
} while (0)

#define HL(DST, T) do {                                                       \
    DST[0] = *(const bf16x8*)&hr[hrow0 + (T) * 16];                           \
    DST[1] = *(const bf16x8*)&hr[hrow1 + (T) * 16];                           \
} while (0)

#define MT(WA, HBX)                                                           \
    _Pragma("unroll") for (int m = 0; m < 2; ++m)                             \
    _Pragma("unroll") for (int g = 0; g < 4; ++g)                             \
        acc[m][g] = __builtin_amdgcn_mfma_f32_32x32x16_bf16(                  \
            WA[g], HBX[m], acc[m][g], 0, 0, 0);

// one pipeline stage: consume tile K from (AW,HBX), refill AW<-K+3, HBX<-K+2
#define STG(K, AW, HBX) do { MT(AW, HBX); WL(AW, (K) + 3); HL(HBX, (K) + 2); } while (0)

__global__ __launch_bounds__(512, 2) void lstm_main(
    const float* __restrict__ x, const u16* __restrict__ whext,
    const u16* __restrict__ wdp, float* __restrict__ out) {
    __shared__ __align__(16) u16 hbuf[2 * HB];   // h double buffer, 75,776 B
    __shared__ __align__(16) u16 wlds[32768];    // parked weight tiles 0,1 (64KB)
    __shared__ int flag16[4];   // pred-feedback publish counters (monotone)

    const int tid = threadIdx.x;
    const int w = tid >> 6;        // wave 0..7 -> units [32w, 32w+32)
    const int l = tid & 63;
    const int l31 = l & 31;
    const int lh = l >> 5;
    const long long rowBase = (long long)blockIdx.x * 64;

    {   // zero both h buffers; copy parked weight tiles 0,1 into LDS
        int4 z = make_int4(0, 0, 0, 0);
        for (int i = tid; i < 4736; i += 512) ((int4*)hbuf)[i] = z;
        for (int i = tid; i < 4096; i += 512)          // 65,536 B, once
            ((int4*)wlds)[i] = ((const int4*)whext)[i];
        if (tid < 4) flag16[tid] = 0;
    }
    sync_lds();
    if (tid < 64) {
        hbuf[tid * PITCH + 260] = (u16)0x3F80;        // bias-1 col, buffer 0
        hbuf[HB + tid * PITCH + 260] = (u16)0x3F80;   // and buffer 1
        const float4 xv = *(const float4*)(x + (rowBase + tid) * 192);
        uint2* p = (uint2*)&hbuf[tid * PITCH + 256];   // x_0 -> buffer 0
        *p = make_uint2(pk_bf16(xv.x, xv.y), pk_bf16(xv.z, xv.w));
    }

    const char* __restrict__ wpw = (const char*)whext + (size_t)w * 4096;
    const char* __restrict__ wlp = (const char*)wlds + (size_t)w * 4096;
    const char* __restrict__ dp = (const char*)wdp;
    const int voffl = l * 16;
    const int hrow0 = l31 * PITCH + lh * 8;          // B-frag row, m=0 (elems)
    const int hrow1 = (32 + l31) * PITCH + lh * 8;   // m=1

    f32x16 c[2] = {};      // cell state: m -> batch 32m+l31; reg r -> unit
                           // 32w + (r&3) + 8*(r>>2) + 4*lh
    bf16x8 aw0[4], aw1[4], aw2[4];   // ring-3 GLOBAL tiles; tile t slot (t-2)%3
    WL(aw0, 2);            // tiles 2,3,4 in flight across the first barrier
    WL(aw1, 3);
    WL(aw2, 4);

    for (int step = 0; step < STEPS; ++step) {
        const u16* hr = hbuf + (step & 1) * HB;      // read buffer
        u16* hrw = hbuf + (step & 1) * HB;           // same buffer, writable
        u16* hw = hbuf + ((step & 1) ^ 1) * HB;      // write buffer

        // wave 0: issue next warmup x load now; used ~10us later at step end
        float4 xv = make_float4(0.f, 0.f, 0.f, 0.f);
        if (w == 0 && step < WARM - 1)
            xv = *(const float4*)(x + (rowBase + l) * 192 + (step + 1) * 4);

        sync_lds();   // hr ready; prior reads of hw done; aw0..2 in flight

        // ---- pred for output s = step-WARM, folded into this GEMM phase
        // (R18-proven). Reads hr h-cols 0..255; writes out + feedback x
        // (hr cols 256..259, consumed at stage 14 after wait4(flag16)).
        if (step >= WARM && w < 4) {
            f32x4 pacc = {};
            const int col = l & 15;                     // batch within tile
            const int prow = (16 * w + col) * PITCH + (l >> 4) * 8;
#pragma unroll
            for (int kc = 0; kc < 9; ++kc) {            // K32 chunks 0..8
                bf16x8 hbp = *(const bf16x8*)&hr[prow + kc * 32];
                bf16x8 wap = *(const bf16x8*)(dp + ((size_t)kc * 64 + l) * 16);
                pacc = __builtin_amdgcn_mfma_f32_16x16x32_bf16(wap, hbp, pacc, 0, 0, 0);
            }
            if ((l >> 4) == 0) {   // quad 0: regs 0..3 = features 0..3
                int s = step - WARM;
                int batch = 16 * w + col;
                *(float4*)&out[((rowBase + batch) * 24 + s) * 4] =
                    make_float4(pacc[0], pacc[1], pacc[2], pacc[3]);
                *(uint2*)&hrw[batch * PITCH + 256] =   // feedback as x_step
                    make_uint2(pk_bf16(pacc[0], pacc[1]), pk_bf16(pacc[2], pacc[3]));
            }
            asm volatile("s_waitcnt lgkmcnt(0)" ::: "memory");
            if (l == 0) *(volatile int*)&flag16[w] = step - WARM + 1;
        }

        f32x16 acc[2][4] = {};   // [batch-tile m][gate]
        bf16x8 hb0[2], hb1[2];   // 2-ring: tile k lives in hb[k&1]
        HL(hb0, 0);
        HL(hb1, 1);

        // ---- stages 0,1: parked tiles from LDS (one reused awl buffer;
        // second read's latency hides under stage-0's MFMAs + wave overlap).
        {
            bf16x8 awl[4];
            WLL(awl, 0);
            MT(awl, hb0); HL(hb0, 2);
            WLL(awl, 1);
            MT(awl, hb1); HL(hb1, 3);
        }

        // ---- global tiles 2..16, ring-3 (slot (t-2)%3). Stage t:
        // MT(slot, hb[t&1]); WL slot <- t+3; HL hb[t&1] <- t+2.
#pragma unroll 1
        for (int t = 2; t < 14; t += 6) {   // t = 2..13, fixed slot pattern
            STG(t + 0, aw0, hb0);
            STG(t + 1, aw1, hb1);
            STG(t + 2, aw2, hb0);
            STG(t + 3, aw0, hb1);
            STG(t + 4, aw1, hb0);
            STG(t + 5, aw2, hb1);
        }
        MT(aw0, hb0); WL(aw0, 2);                // t=14; prestage next tile 2
        if (step >= WARM) wait4(flag16, step - WARM + 1);   // x_step published?
        HL(hb0, 16);
        MT(aw1, hb1); WL(aw1, 3);                // t=15; prestage next tile 3
        MT(aw2, hb0); WL(aw2, 4);                // t=16; prestage next tile 4
        // aw0..2 now hold NEXT step's tiles 2,3,4 (slots 0,1,2 = where
        // stages t=2,3,4 read them; 15 global tiles, 15%3==0 -> no rotation)

        // gates; lane holds batch 32m+l31, units 32w + (r&3)+8*(r>>2)+4*lh.
        // 7 transcendentals/elem: 5 exp2 + 2 rcp. Bit-identical to R18.
#pragma unroll
        for (int m = 0; m < 2; ++m) {
            const int hwrow = (32 * m + l31) * PITCH + 32 * w + 4 * lh;
#pragma unroll
            for (int q = 0; q < 4; ++q) {
                unsigned pk[2];
#pragma unroll
                for (int hp = 0; hp < 2; ++hp) {
                    float h2[2];
#pragma unroll
                    for (int rr = 0; rr < 2; ++rr) {
                        const int r = q * 4 + hp * 2 + rr;
                        float ei = __builtin_amdgcn_exp2f(-acc[m][0][r]);
                        float ef = __builtin_amdgcn_exp2f(-acc[m][1][r]);
                        float eg = __builtin_amdgcn_exp2f(-acc[m][2][r]);
                        float eo = __builtin_amdgcn_exp2f(-acc[m][3][r]);
                        float ai = 1.0f + ei, af = 1.0f + ef;
                        float ag = 1.0f + eg, ao = 1.0f + eo;
                        float P  = ai * ag;
                        float rD = __builtin_amdgcn_rcpf(P * af);
                        float cn = fmaf(c[m][r] * P, rD, (1.0f - eg) * af * rD);
                        c[m][r] = cn;
                        float ec = __builtin_amdgcn_exp2f(-LOG2E2 * cn);
                        float rE = __builtin_amdgcn_rcpf(ao * (1.0f + ec));
                        h2[rr] = (1.0f - ec) * rE;
                    }
                    pk[hp] = pk_bf16(h2[0], h2[1]);
                }
                *(uint2*)&hw[hwrow + 8 * q] = make_uint2(pk[0], pk[1]);
            }
        }

        if (step < WARM - 1) {
            if (w == 0) {   // x_{step+1} (prefetched at step top) -> hw
                uint2* p = (uint2*)&hw[l * PITCH + 256];
                *p = make_uint2(pk_bf16(xv.x, xv.y), pk_bf16(xv.z, xv.w));
            }
        }
        // AR steps: pred for this step's h runs at the TOP of the next
        // iteration, overlapped with the GEMM phase (no second barrier).
    }

    // ---- epilogue: last prediction (s = 23) from h_71 (no feedback needed)
    sync_lds();
    if (w < 4) {
        const u16* hf = hbuf + (((STEPS - 1) & 1) ^ 1) * HB;
        f32x4 pacc = {};
        const int col = l & 15;
        const int prow = (16 * w + col) * PITCH + (l >> 4) * 8;
#pragma unroll
        for (int kc = 0; kc < 9; ++kc) {
            bf16x8 hbp = *(const bf16x8*)&hf[prow + kc * 32];
            bf16x8 wap = *(const bf16x8*)(dp + ((size_t)kc * 64 + l) * 16);
            pacc = __builtin_amdgcn_mfma_f32_16x16x32_bf16(wap, hbp, pacc, 0, 0, 0);
        }
        if ((l >> 4) == 0) {
            int batch = 16 * w + col;
            *(float4*)&out[((rowBase + batch) * 24 + 23) * 4] =
                make_float4(pacc[0], pacc[1], pacc[2], pacc[3]);
        }
    }
}

extern "C" void kernel_launch(void* const* d_in, const int* in_sizes, int n_in,
                              void* d_out, int out_size, void* d_ws, size_t ws_size,
                              hipStream_t stream) {
    const float* x  = (const float*)d_in[0];   // [16384,48,4]
    const float* Wx = (const float*)d_in[1];   // [4,1024]
    const float* Wh = (const float*)d_in[2];   // [256,1024]
    const float* b  = (const float*)d_in[3];   // [1024]
    const float* Wd = (const float*)d_in[4];   // [256,4]
    const float* bd = (const float*)d_in[5];   // [4]
    float* out = (float*)d_out;                // [16384,24,4] fp32

    u16* whext = (u16*)d_ws;                        // 17*32*64*16 = 557056 B
    u16* wdp = (u16*)((char*)d_ws + 557056);        // 9216 B

    prep_weights<<<(34816 + 576 + 255) / 256, 256, 0, stream>>>(Wx, Wh, b, Wd, bd, whext, wdp);
    lstm_main<<<256, 512, 0, stream>>>(x, whext, wdp, out);
}